// Round 10
// baseline (292.078 us; speedup 1.0000x reference)
//
#include <hip/hip_runtime.h>

// RelationNet: B=16, N=16, K=8, H=128, 2H=256
// out[b,n1,o] = mean over (n2,k1,k2) of relu(W3 relu(W2 relu(A[b,n1,k1]+Bv[b,n2,k2])))
// A = enc @ W1[:, :128]^T, Bv = enc @ W1[:, 128:]^T  (layer 1 factors).
// Numerics (validated R5..R9, absmax 3.9e-3): x=fp16 RN, W=fp16 hi+lo, 2 MFMA/product.
// R10: R9's swapped-operand MFMA (D[o][r] = mfma(A=W, B=x)), but ONE 66KB LDS
//   buffer reused for o1 then o2t (3 barriers) -> 2 blocks/CU (was 1).
//   Linear layout (R9's XOR swizzle removed: it *increased* conflicts).

typedef _Float16 f16;
typedef __attribute__((ext_vector_type(4))) _Float16 f16x4;
typedef __attribute__((ext_vector_type(8))) _Float16 f16x8;
typedef __attribute__((ext_vector_type(4))) float    f32x4;

#define STRH 264   // f16 row stride: 528B (16B-aligned); rows spread banks by 4

// ws layout in floats:
//   [0)        W1aT  128*256 fp32     [32768) W1bT 128*256 fp32
//   [65536)    W2h   256*256 fp16     [98304) W2l
//   [131072)   W3h   256*256 fp16     [163840) W3l
//   [196608)   A1    2048*256 fp32    [720896) B1 2048*256 fp32
//   [1245184)  partial 4096*256 fp32

__global__ void prep_w(const float* __restrict__ W1,
                       const float* __restrict__ W2,
                       const float* __restrict__ W3,
                       float* __restrict__ ws) {
    int e = blockIdx.x * 256 + threadIdx.x;   // 0..65535
    int hi = e >> 8;
    int o  = e & 255;
    if (e < 32768) {
        ws[e]         = W1[o * 256 + hi];        // W1aT[h][o]
        ws[32768 + e] = W1[o * 256 + 128 + hi];  // W1bT[h][o]
    }
    f16* W2h = (f16*)(ws + 65536);
    f16* W2l = (f16*)(ws + 98304);
    f16* W3h = (f16*)(ws + 131072);
    f16* W3l = (f16*)(ws + 163840);
    float w2 = W2[e];
    f16 h2 = (f16)w2;
    W2h[e] = h2;
    W2l[e] = (f16)(w2 - (float)h2);
    float w3 = W3[e];
    f16 h3 = (f16)w3;
    W3h[e] = h3;
    W3l[e] = (f16)(w3 - (float)h3);
}

__global__ void prep_ab(const float* __restrict__ enc,
                        const float* __restrict__ ws,
                        float* __restrict__ A1,
                        float* __restrict__ B1) {
    __shared__ float es[128];
    int row = blockIdx.x;       // 0..2047 = (b*16+n)*8+k
    int o = threadIdx.x;        // 0..255
    if (o < 128) es[o] = enc[row * 128 + o];
    __syncthreads();
    const float* __restrict__ W1aT = ws;
    const float* __restrict__ W1bT = ws + 32768;
    float a = 0.f, bv = 0.f;
#pragma unroll 8
    for (int h = 0; h < 128; ++h) {
        float ev = es[h];
        a  += ev * W1aT[h * 256 + o];
        bv += ev * W1bT[h * 256 + o];
    }
    A1[row * 256 + o] = a;
    B1[row * 256 + o] = bv;
}

__global__ __launch_bounds__(512, 2)
void relnet_main(const float* __restrict__ A1, const float* __restrict__ B1,
                 const f16* __restrict__ W2h, const f16* __restrict__ W2l,
                 const f16* __restrict__ W3h, const f16* __restrict__ W3l,
                 float* __restrict__ partial) {
    __shared__ alignas(16) f16 xb[128][STRH];   // 67.6 KB, o1 then o2t

    const int n2p = blockIdx.x;   // 0..7: pair of n2 values
    const int n1  = blockIdx.y, b = blockIdx.z;
    const int tid  = threadIdx.x;
    const int lane = tid & 63;
    const int w    = tid >> 6;     // wave 0..7 -> 32-col (o) slice
    const int lr   = lane & 15;    // A row (=o) / B col (=r) / D col (=r)
    const int lg   = lane >> 4;    // k-group; D row-group
    const int ko   = lg * 8;
    const int cb   = w * 32;

    const int bn1 = b * 16 + n1;

    // ---- W2 fragments -> registers (issued first; latency under build) ----
    f16x8 wr[2][2][8];   // [cf][hi/lo][kt]
#pragma unroll
    for (int cf = 0; cf < 2; ++cf) {
        const int col = cb + cf * 16 + lr;
#pragma unroll
        for (int kt = 0; kt < 8; ++kt) {
            wr[cf][0][kt] = *(const f16x8*)&W2h[col * 256 + kt * 32 + ko];
            wr[cf][1][kt] = *(const f16x8*)&W2l[col * 256 + kt * 32 + ko];
        }
    }

    // ---- build o1[128][256] = fp16(relu(A[k1]+Bv[k2])) into LDS ----
    {
        const int r = (w & 1) * 64 + lane;   // row 0..127 (unique with g)
        const int g = w >> 1;                // 64-col chunk 0..3
        const int k1 = (r >> 3) & 7, k2 = r & 7;
        const float* __restrict__ ap = A1 + (bn1 * 8 + k1) * 256 + g * 64;
        const float* __restrict__ bp = B1 + ((b * 16 + n2p * 2 + (r >> 6)) * 8 + k2) * 256 + g * 64;
#pragma unroll
        for (int i = 0; i < 8; ++i) {
            float4 a0 = *(const float4*)&ap[i * 8];
            float4 a1 = *(const float4*)&ap[i * 8 + 4];
            float4 b0 = *(const float4*)&bp[i * 8];
            float4 b1 = *(const float4*)&bp[i * 8 + 4];
            f16x8 x;
            x[0] = (f16)fmaxf(a0.x + b0.x, 0.f);
            x[1] = (f16)fmaxf(a0.y + b0.y, 0.f);
            x[2] = (f16)fmaxf(a0.z + b0.z, 0.f);
            x[3] = (f16)fmaxf(a0.w + b0.w, 0.f);
            x[4] = (f16)fmaxf(a1.x + b1.x, 0.f);
            x[5] = (f16)fmaxf(a1.y + b1.y, 0.f);
            x[6] = (f16)fmaxf(a1.z + b1.z, 0.f);
            x[7] = (f16)fmaxf(a1.w + b1.w, 0.f);
            *(f16x8*)&xb[r][g * 64 + i * 8] = x;
        }
    }

    f32x4 acc[8][2];
#pragma unroll
    for (int fm = 0; fm < 8; ++fm)
#pragma unroll
        for (int cf = 0; cf < 2; ++cf) acc[fm][cf] = (f32x4){0.f, 0.f, 0.f, 0.f};

    __syncthreads();   // (1) o1 ready

    // ================= layer 2: D[o][r] += W2 * x1 =================
#pragma unroll
    for (int kt = 0; kt < 8; ++kt) {
        f16x8 x[8];
#pragma unroll
        for (int fm = 0; fm < 8; ++fm)
            x[fm] = *(const f16x8*)&xb[fm * 16 + lr][kt * 32 + ko];
#pragma unroll
        for (int fm = 0; fm < 8; ++fm)
#pragma unroll
            for (int cf = 0; cf < 2; ++cf) {
                acc[fm][cf] = __builtin_amdgcn_mfma_f32_16x16x32_f16(wr[cf][0][kt], x[fm], acc[fm][cf], 0, 0, 0);
                acc[fm][cf] = __builtin_amdgcn_mfma_f32_16x16x32_f16(wr[cf][1][kt], x[fm], acc[fm][cf], 0, 0, 0);
            }
    }

    // ---- issue W3 loads (latency hidden under barrier + writeback) ----
#pragma unroll
    for (int cf = 0; cf < 2; ++cf) {
        const int col = cb + cf * 16 + lr;
#pragma unroll
        for (int kt = 0; kt < 8; ++kt) {
            wr[cf][0][kt] = *(const f16x8*)&W3h[col * 256 + kt * 32 + ko];
            wr[cf][1][kt] = *(const f16x8*)&W3l[col * 256 + kt * 32 + ko];
        }
    }

    __syncthreads();   // (2) all layer-2 reads of xb done -> safe to overwrite

    // ---- o2t[r][o] = fp16(relu(acc)): b64 stores (4 consecutive o) ----
#pragma unroll
    for (int fm = 0; fm < 8; ++fm) {
        const int rr = fm * 16 + lr;
#pragma unroll
        for (int cf = 0; cf < 2; ++cf) {
            f16x4 v;
#pragma unroll
            for (int j = 0; j < 4; ++j) v[j] = (f16)fmaxf(acc[fm][cf][j], 0.f);
            *(f16x4*)&xb[rr][cb + cf * 16 + lg * 4] = v;
        }
    }

#pragma unroll
    for (int fm = 0; fm < 8; ++fm)
#pragma unroll
        for (int cf = 0; cf < 2; ++cf) acc[fm][cf] = (f32x4){0.f, 0.f, 0.f, 0.f};

    __syncthreads();   // (3) o2t ready

    // ================= layer 3: D[o][r] += W3 * x2 =================
#pragma unroll
    for (int kt = 0; kt < 8; ++kt) {
        f16x8 x[8];
#pragma unroll
        for (int fm = 0; fm < 8; ++fm)
            x[fm] = *(const f16x8*)&xb[fm * 16 + lr][kt * 32 + ko];
#pragma unroll
        for (int fm = 0; fm < 8; ++fm)
#pragma unroll
            for (int cf = 0; cf < 2; ++cf) {
                acc[fm][cf] = __builtin_amdgcn_mfma_f32_16x16x32_f16(wr[cf][0][kt], x[fm], acc[fm][cf], 0, 0, 0);
                acc[fm][cf] = __builtin_amdgcn_mfma_f32_16x16x32_f16(wr[cf][1][kt], x[fm], acc[fm][cf], 0, 0, 0);
            }
    }

    // ---- relu + sum over r: fm within n2-group, then lr lanes (bits 0..3) ----
    float po[2][2][4];
#pragma unroll
    for (int g = 0; g < 2; ++g)
#pragma unroll
        for (int cf = 0; cf < 2; ++cf)
#pragma unroll
            for (int j = 0; j < 4; ++j) po[g][cf][j] = 0.f;
#pragma unroll
    for (int fm = 0; fm < 8; ++fm) {
        const int g = fm >> 2;
#pragma unroll
        for (int cf = 0; cf < 2; ++cf)
#pragma unroll
            for (int j = 0; j < 4; ++j)
                po[g][cf][j] += fmaxf(acc[fm][cf][j], 0.f);
    }
#pragma unroll
    for (int g = 0; g < 2; ++g)
#pragma unroll
        for (int cf = 0; cf < 2; ++cf)
#pragma unroll
            for (int j = 0; j < 4; ++j) {
                po[g][cf][j] += __shfl_xor(po[g][cf][j], 1);
                po[g][cf][j] += __shfl_xor(po[g][cf][j], 2);
                po[g][cf][j] += __shfl_xor(po[g][cf][j], 4);
                po[g][cf][j] += __shfl_xor(po[g][cf][j], 8);
            }
    if (lr == 0) {
#pragma unroll
        for (int g = 0; g < 2; ++g) {
            float* pb = partial + ((bn1 * 16 + n2p * 2 + g) * 256) + cb + lg * 4;
#pragma unroll
            for (int cf = 0; cf < 2; ++cf)
                *(float4*)&pb[cf * 16] =
                    make_float4(po[g][cf][0], po[g][cf][1], po[g][cf][2], po[g][cf][3]);
        }
    }
}

__global__ void reduce_mean(const float* __restrict__ partial,
                            float* __restrict__ out) {
    int e = blockIdx.x * 256 + threadIdx.x;  // (b*16+n1)*256+o
    int bn1 = e >> 8, o = e & 255;
    float s = 0.f;
#pragma unroll
    for (int n2 = 0; n2 < 16; ++n2)
        s += partial[(bn1 * 16 + n2) * 256 + o];
    out[e] = s * (1.0f / 1024.0f);
}

extern "C" void kernel_launch(void* const* d_in, const int* in_sizes, int n_in,
                              void* d_out, int out_size, void* d_ws, size_t ws_size,
                              hipStream_t stream) {
    const float* enc = (const float*)d_in[0];
    const float* W1  = (const float*)d_in[1];
    const float* W2  = (const float*)d_in[2];
    const float* W3  = (const float*)d_in[3];
    float* ws  = (float*)d_ws;
    float* out = (float*)d_out;

    const f16* W2h = (const f16*)(ws + 65536);
    const f16* W2l = (const f16*)(ws + 98304);
    const f16* W3h = (const f16*)(ws + 131072);
    const f16* W3l = (const f16*)(ws + 163840);
    float* A1   = ws + 196608;
    float* B1   = ws + 720896;
    float* part = ws + 1245184;

    prep_w<<<256, 256, 0, stream>>>(W1, W2, W3, ws);
    prep_ab<<<2048, 256, 0, stream>>>(enc, ws, A1, B1);
    relnet_main<<<dim3(8, 16, 16), 512, 0, stream>>>(A1, B1, W2h, W2l, W3h, W3l, part);
    reduce_mean<<<256, 256, 0, stream>>>(part, out);
}